// Round 1
// baseline (8580.956 us; speedup 1.0000x reference)
//
#include <hip/hip_runtime.h>
#include <hip/hip_bf16.h>

#define BB   64      // batch
#define SS   1024    // state size
#define HH   256     // h size
#define OUTD 768     // per-cell output size
#define TT   16      // time steps
#define DOUT 512     // adaptor output
#define DIN  512     // raw input feature size

// ---------------------------------------------------------------------------
// Fused cell kernel: one (t, layer) phase.
// grid = 256 blocks, block = 256 threads = 4 waves.
// Wave w of block b owns state column j = b*4 + w; lane = batch row (64 rows).
// Computes g[r, {j, S+j, 2S+j, 3S+j}] = xh[r,:] . W[rows], then applies the
// LSTM-style gate update and scatters out / h / c.
// xh = concat(u, prevH, dH) handled as up-to-3 K-segments (skipped at t==0).
// ---------------------------------------------------------------------------
__global__ __launch_bounds__(256) void cell_kernel(
    const float* __restrict__ u, int Ku,
    const float* __restrict__ W, int Kin,
    const float* __restrict__ bias,
    const float* __restrict__ hPrev,
    const float* __restrict__ hDel,
    const float* __restrict__ cPrev,
    const float* __restrict__ cDel,
    int prev_ok, int delayed_ok,
    float* __restrict__ outp,          // B x OUTD (first OUTD cols of whole)
    const float* __restrict__ resid,   // nullptr or B x OUTD, added to outp
    float* __restrict__ hOut,          // B x HH
    float* __restrict__ cOut)          // B x SS
{
    __shared__ float lds[64 * 68];     // 64 rows x 64 k, pitch 68 (16B aligned)

    const int tid  = threadIdx.x;
    const int lane = tid & 63;
    const int wave = tid >> 6;
    const int j    = blockIdx.x * 4 + wave;
    const int ju   = __builtin_amdgcn_readfirstlane(j);

    float acc0 = 0.f, acc1 = 0.f, acc2 = 0.f, acc3 = 0.f;

    const float* segp[3];
    int          segl[3];
    int nseg = 0;
    segp[nseg] = u;  segl[nseg] = Ku; nseg++;
    if (prev_ok) {
        segp[nseg] = hPrev; segl[nseg] = HH; nseg++;
        segp[nseg] = hDel;  segl[nseg] = HH; nseg++;
    }

    int wcol = 0;  // running column offset into W
    for (int s = 0; s < nseg; ++s) {
        const float* src = segp[s];
        const int    len = segl[s];
        for (int k0 = 0; k0 < len; k0 += 64) {
            // cooperative load: 64 rows x 64 k, coalesced per row
            #pragma unroll
            for (int i = 0; i < 16; ++i) {
                int e = i * 256 + tid;
                int r = e >> 6, k = e & 63;
                lds[r * 68 + k] = src[(size_t)r * len + k0 + k];
            }
            __syncthreads();

            const float* w0 = W + (size_t)(0 * SS + ju) * Kin + wcol + k0;
            const float* w1 = W + (size_t)(1 * SS + ju) * Kin + wcol + k0;
            const float* w2 = W + (size_t)(2 * SS + ju) * Kin + wcol + k0;
            const float* w3 = W + (size_t)(3 * SS + ju) * Kin + wcol + k0;
            #pragma unroll
            for (int k4 = 0; k4 < 16; ++k4) {
                float4 xv = *reinterpret_cast<const float4*>(&lds[lane * 68 + k4 * 4]);
                float4 a0 = *reinterpret_cast<const float4*>(w0 + k4 * 4);
                float4 a1 = *reinterpret_cast<const float4*>(w1 + k4 * 4);
                float4 a2 = *reinterpret_cast<const float4*>(w2 + k4 * 4);
                float4 a3 = *reinterpret_cast<const float4*>(w3 + k4 * 4);
                acc0 += xv.x * a0.x + xv.y * a0.y + xv.z * a0.z + xv.w * a0.w;
                acc1 += xv.x * a1.x + xv.y * a1.y + xv.z * a1.z + xv.w * a1.w;
                acc2 += xv.x * a2.x + xv.y * a2.y + xv.z * a2.z + xv.w * a2.w;
                acc3 += xv.x * a3.x + xv.y * a3.y + xv.z * a3.z + xv.w * a3.w;
            }
            __syncthreads();
        }
        wcol += len;
    }

    // ---- gate epilogue (lane = row r, column ju) ----
    const int r = lane;
    float g0 = acc0 + bias[ju];
    float g1 = acc1 + bias[SS + ju];
    float g2 = acc2 + bias[2 * SS + ju];
    float g3 = acc3 + bias[3 * SS + ju];

    float f = 1.f / (1.f + __expf(-(g0 + 1.f)));
    float n = tanhf(g1);
    float a = 1.f / (1.f + __expf(-g2));
    float o = 1.f / (1.f + __expf(-g3));

    float pC = prev_ok ? cPrev[(size_t)r * SS + ju] : 0.f;
    float dC = delayed_ok ? cDel[(size_t)r * SS + ju] : pC;
    float wC = delayed_ok ? (a * pC + (1.f - a) * dC) : pC;
    float nf = prev_ok ? (f * wC + (1.f - f) * n) : n;
    float wh = o * nf;

    cOut[(size_t)r * SS + ju] = nf;
    if (ju < OUTD) {
        float v = wh;
        if (resid) v += resid[(size_t)r * OUTD + ju];
        outp[(size_t)r * OUTD + ju] = v;
    } else {
        hOut[(size_t)r * HH + (ju - OUTD)] = wh;
    }
}

// ---------------------------------------------------------------------------
// Adaptor: Y[1024][512] = U[1024][768] @ Wa^T + ba, batched over all T at end.
// Same wave-per-column structure; blockIdx.y selects a 64-row group.
// ---------------------------------------------------------------------------
__global__ __launch_bounds__(256) void adaptor_kernel(
    const float* __restrict__ U,    // [T*B][OUTD]
    const float* __restrict__ Wa,   // [DOUT][OUTD]
    const float* __restrict__ ba,   // [DOUT]
    float* __restrict__ Y)          // [T*B][DOUT]
{
    __shared__ float lds[64 * 68];
    const int tid  = threadIdx.x;
    const int lane = tid & 63;
    const int wave = tid >> 6;
    const int col  = blockIdx.x * 4 + wave;
    const int cu   = __builtin_amdgcn_readfirstlane(col);
    const int row0 = blockIdx.y * 64;

    float acc = 0.f;
    for (int k0 = 0; k0 < OUTD; k0 += 64) {
        #pragma unroll
        for (int i = 0; i < 16; ++i) {
            int e = i * 256 + tid;
            int r = e >> 6, k = e & 63;
            lds[r * 68 + k] = U[(size_t)(row0 + r) * OUTD + k0 + k];
        }
        __syncthreads();
        const float* wrow = Wa + (size_t)cu * OUTD + k0;
        #pragma unroll
        for (int k4 = 0; k4 < 16; ++k4) {
            float4 xv = *reinterpret_cast<const float4*>(&lds[lane * 68 + k4 * 4]);
            float4 wv = *reinterpret_cast<const float4*>(wrow + k4 * 4);
            acc += xv.x * wv.x + xv.y * wv.y + xv.z * wv.z + xv.w * wv.w;
        }
        __syncthreads();
    }
    Y[(size_t)(row0 + lane) * DOUT + cu] = acc + ba[cu];
}

// ---------------------------------------------------------------------------
extern "C" void kernel_launch(void* const* d_in, const int* in_sizes, int n_in,
                              void* d_out, int out_size, void* d_ws, size_t ws_size,
                              hipStream_t stream)
{
    const float* x  = (const float*)d_in[0];
    const float* W0 = (const float*)d_in[1];
    const float* b0 = (const float*)d_in[2];
    const float* W1 = (const float*)d_in[3];
    const float* b1 = (const float*)d_in[4];
    const float* W2 = (const float*)d_in[5];
    const float* b2 = (const float*)d_in[6];
    const float* W3 = (const float*)d_in[7];
    const float* b3 = (const float*)d_in[8];
    const float* Wa = (const float*)d_in[9];
    const float* ba = (const float*)d_in[10];
    float* out = (float*)d_out;

    float* ws = (float*)d_ws;
    float* hBuf = ws;                                   // 4*T*B*H   = 1,048,576 f
    float* cBuf = hBuf + (size_t)4 * TT * BB * HH;      // 4*T*B*S   = 4,194,304 f
    float* outA = cBuf + (size_t)4 * TT * BB * SS;      // B*OUTD
    float* outB = outA + (size_t)BB * OUTD;             // B*OUTD
    float* blockOutAll = outB + (size_t)BB * OUTD;      // T*B*OUTD

    const float* Wl[4] = {W0, W1, W2, W3};
    const float* bl[4] = {b0, b1, b2, b3};
    const int dil[4] = {1, 2, 4, 8};
    const int Kus[4] = {DIN, OUTD, OUTD, OUTD};

    dim3 blk(256), grd(256);
    for (int t = 0; t < TT; ++t) {
        for (int l = 0; l < 4; ++l) {
            const float* u;
            float* outp;
            const float* resid = nullptr;
            if (l == 0)      u = x + (size_t)t * BB * DIN;
            else if (l == 1) u = outA;
            else if (l == 2) u = outB;
            else             u = outA;
            if (l == 0)      outp = outA;
            else if (l == 1) outp = outB;
            else if (l == 2) outp = outA;
            else { outp = blockOutAll + (size_t)t * BB * OUTD; resid = outB; }

            float* hL = hBuf + (size_t)l * TT * BB * HH;
            float* cL = cBuf + (size_t)l * TT * BB * SS;
            const int d = dil[l];
            const int prev_ok = (t > 0) ? 1 : 0;
            const int delayed_ok = (t >= d) ? 1 : 0;
            const int tm1 = (t > 0) ? t - 1 : 0;
            const int td  = delayed_ok ? t - d : tm1;
            const float* hPrev = hL + (size_t)tm1 * BB * HH;
            const float* hDel  = hL + (size_t)td  * BB * HH;
            const float* cPrev = cL + (size_t)tm1 * BB * SS;
            const float* cDel  = cL + (size_t)td  * BB * SS;
            float* hOut = hL + (size_t)t * BB * HH;
            float* cOut = cL + (size_t)t * BB * SS;

            hipLaunchKernelGGL(cell_kernel, grd, blk, 0, stream,
                u, Kus[l], Wl[l], Kus[l] + 2 * HH, bl[l],
                hPrev, hDel, cPrev, cDel, prev_ok, delayed_ok,
                outp, resid, hOut, cOut);
        }
    }

    dim3 agrd(DOUT / 4, (TT * BB) / 64);
    hipLaunchKernelGGL(adaptor_kernel, agrd, blk, 0, stream,
                       blockOutAll, Wa, ba, out);
}

// Round 2
// 3072.557 us; speedup vs baseline: 2.7928x; 2.7928x over previous
//
#include <hip/hip_runtime.h>
#include <hip/hip_bf16.h>

#define BB   64      // batch
#define SS   1024    // state size
#define HH   256     // h size
#define OUTD 768     // per-cell output size
#define TT   16      // time steps
#define DOUT 512     // adaptor output
#define DIN  512     // raw input feature size

// ---------------------------------------------------------------------------
// Fused cell kernel: one (t, layer) phase.
// grid = 256 blocks, block = 256 threads = 4 waves.
// Block b owns 4 state columns j0=b*4..+3 (i.e. 16 gate-rows of W).
// Wave w owns column j = j0 + w; lane = batch row r; acc[g] = gate g.
// Both xh and the 16 W gate-rows are LDS-staged per 64-wide k-tile with
// fully coalesced cooperative loads (fixes the wave-uniform W-fetch wall).
// ---------------------------------------------------------------------------
__global__ __launch_bounds__(256) void cell_kernel(
    const float* __restrict__ u, int Ku,
    const float* __restrict__ W, int Kin,
    const float* __restrict__ bias,
    const float* __restrict__ hPrev,
    const float* __restrict__ hDel,
    const float* __restrict__ cPrev,
    const float* __restrict__ cDel,
    int prev_ok, int delayed_ok,
    float* __restrict__ outp,          // B x OUTD (first OUTD cols of whole)
    const float* __restrict__ resid,   // nullptr or B x OUTD, added to outp
    float* __restrict__ hOut,          // B x HH
    float* __restrict__ cOut)          // B x SS
{
    __shared__ float lds_x[64 * 68];   // 64 rows x 64 k, pitch 68 (16B-aligned rows)
    __shared__ float lds_w[16 * 68];   // 16 gate-rows x 64 k

    const int tid  = threadIdx.x;
    const int lane = tid & 63;
    const int wave = tid >> 6;
    const int j0   = blockIdx.x * 4;
    const int j    = j0 + wave;
    const int ju   = __builtin_amdgcn_readfirstlane(j);

    float acc0 = 0.f, acc1 = 0.f, acc2 = 0.f, acc3 = 0.f;

    const float* segp[3];
    int          segl[3];
    int nseg = 0;
    segp[nseg] = u;  segl[nseg] = Ku; nseg++;
    if (prev_ok) {
        segp[nseg] = hPrev; segl[nseg] = HH; nseg++;
        segp[nseg] = hDel;  segl[nseg] = HH; nseg++;
    }

    // staging indices (constant per thread)
    const int xr  = tid >> 2;          // with 4 iters: row = (i*256+tid)>>4
    const int wrow_id = tid >> 4;      // 0..15
    const int wk4     = tid & 15;      // 0..15
    const int wg      = wrow_id >> 2;  // gate
    const int wjj     = wrow_id & 3;   // column-within-block
    const size_t wgrow = (size_t)(wg * SS + j0 + wjj) * Kin;
    (void)xr;

    int wcol = 0;  // running column offset into W
    for (int s = 0; s < nseg; ++s) {
        const float* src = segp[s];
        const int    len = segl[s];
        for (int k0 = 0; k0 < len; k0 += 64) {
            // ---- stage xh tile: 64 rows x 64 k (1024 float4, 4 per thread)
            #pragma unroll
            for (int i = 0; i < 4; ++i) {
                int e  = i * 256 + tid;
                int r  = e >> 4;          // 0..63
                int k4 = e & 15;          // 0..15
                float4 v = *reinterpret_cast<const float4*>(
                    src + (size_t)r * len + k0 + k4 * 4);
                *reinterpret_cast<float4*>(&lds_x[r * 68 + k4 * 4]) = v;
            }
            // ---- stage W tile: 16 gate-rows x 64 k (256 float4, 1 per thread)
            {
                float4 v = *reinterpret_cast<const float4*>(
                    W + wgrow + wcol + k0 + wk4 * 4);
                *reinterpret_cast<float4*>(&lds_w[wrow_id * 68 + wk4 * 4]) = v;
            }
            __syncthreads();

            #pragma unroll
            for (int k4 = 0; k4 < 16; ++k4) {
                float4 xv = *reinterpret_cast<const float4*>(&lds_x[lane * 68 + k4 * 4]);
                float4 w0 = *reinterpret_cast<const float4*>(&lds_w[(0 * 4 + wave) * 68 + k4 * 4]);
                float4 w1 = *reinterpret_cast<const float4*>(&lds_w[(1 * 4 + wave) * 68 + k4 * 4]);
                float4 w2 = *reinterpret_cast<const float4*>(&lds_w[(2 * 4 + wave) * 68 + k4 * 4]);
                float4 w3 = *reinterpret_cast<const float4*>(&lds_w[(3 * 4 + wave) * 68 + k4 * 4]);
                acc0 += xv.x * w0.x + xv.y * w0.y + xv.z * w0.z + xv.w * w0.w;
                acc1 += xv.x * w1.x + xv.y * w1.y + xv.z * w1.z + xv.w * w1.w;
                acc2 += xv.x * w2.x + xv.y * w2.y + xv.z * w2.z + xv.w * w2.w;
                acc3 += xv.x * w3.x + xv.y * w3.y + xv.z * w3.z + xv.w * w3.w;
            }
            __syncthreads();
        }
        wcol += len;
    }

    // ---- gate epilogue (lane = row r, column ju) ----
    const int r = lane;
    float g0 = acc0 + bias[ju];
    float g1 = acc1 + bias[SS + ju];
    float g2 = acc2 + bias[2 * SS + ju];
    float g3 = acc3 + bias[3 * SS + ju];

    float f = 1.f / (1.f + __expf(-(g0 + 1.f)));
    float n = tanhf(g1);
    float a = 1.f / (1.f + __expf(-g2));
    float o = 1.f / (1.f + __expf(-g3));

    float pC = prev_ok ? cPrev[(size_t)r * SS + ju] : 0.f;
    float dC = delayed_ok ? cDel[(size_t)r * SS + ju] : pC;
    float wC = delayed_ok ? (a * pC + (1.f - a) * dC) : pC;
    float nf = prev_ok ? (f * wC + (1.f - f) * n) : n;
    float wh = o * nf;

    cOut[(size_t)r * SS + ju] = nf;
    if (ju < OUTD) {
        float v = wh;
        if (resid) v += resid[(size_t)r * OUTD + ju];
        outp[(size_t)r * OUTD + ju] = v;
    } else {
        hOut[(size_t)r * HH + (ju - OUTD)] = wh;
    }
}

// ---------------------------------------------------------------------------
// Adaptor: Y[1024][512] = U[1024][768] @ Wa^T + ba, batched over all T at end.
// Same coalesced W-staging structure: block owns 16 output cols.
// ---------------------------------------------------------------------------
__global__ __launch_bounds__(256) void adaptor_kernel(
    const float* __restrict__ U,    // [T*B][OUTD]
    const float* __restrict__ Wa,   // [DOUT][OUTD]
    const float* __restrict__ ba,   // [DOUT]
    float* __restrict__ Y)          // [T*B][DOUT]
{
    __shared__ float lds_x[64 * 68];
    __shared__ float lds_w[16 * 68];
    const int tid  = threadIdx.x;
    const int lane = tid & 63;
    const int wave = tid >> 6;
    const int c0   = blockIdx.x * 16;       // 16 output cols per block
    const int row0 = blockIdx.y * 64;

    const int wrow_id = tid >> 4;           // 0..15 (col-within-block)
    const int wk4     = tid & 15;

    float acc[4] = {0.f, 0.f, 0.f, 0.f};    // wave handles cols c0+wave*4..+3

    for (int k0 = 0; k0 < OUTD; k0 += 64) {
        #pragma unroll
        for (int i = 0; i < 4; ++i) {
            int e  = i * 256 + tid;
            int r  = e >> 4;
            int k4 = e & 15;
            float4 v = *reinterpret_cast<const float4*>(
                U + (size_t)(row0 + r) * OUTD + k0 + k4 * 4);
            *reinterpret_cast<float4*>(&lds_x[r * 68 + k4 * 4]) = v;
        }
        {
            float4 v = *reinterpret_cast<const float4*>(
                Wa + (size_t)(c0 + wrow_id) * OUTD + k0 + wk4 * 4);
            *reinterpret_cast<float4*>(&lds_w[wrow_id * 68 + wk4 * 4]) = v;
        }
        __syncthreads();
        #pragma unroll
        for (int k4 = 0; k4 < 16; ++k4) {
            float4 xv = *reinterpret_cast<const float4*>(&lds_x[lane * 68 + k4 * 4]);
            #pragma unroll
            for (int cc = 0; cc < 4; ++cc) {
                float4 wv = *reinterpret_cast<const float4*>(
                    &lds_w[(wave * 4 + cc) * 68 + k4 * 4]);
                acc[cc] += xv.x * wv.x + xv.y * wv.y + xv.z * wv.z + xv.w * wv.w;
            }
        }
        __syncthreads();
    }
    #pragma unroll
    for (int cc = 0; cc < 4; ++cc) {
        int c = c0 + wave * 4 + cc;
        Y[(size_t)(row0 + lane) * DOUT + c] = acc[cc] + ba[c];
    }
}

// ---------------------------------------------------------------------------
extern "C" void kernel_launch(void* const* d_in, const int* in_sizes, int n_in,
                              void* d_out, int out_size, void* d_ws, size_t ws_size,
                              hipStream_t stream)
{
    const float* x  = (const float*)d_in[0];
    const float* W0 = (const float*)d_in[1];
    const float* b0 = (const float*)d_in[2];
    const float* W1 = (const float*)d_in[3];
    const float* b1 = (const float*)d_in[4];
    const float* W2 = (const float*)d_in[5];
    const float* b2 = (const float*)d_in[6];
    const float* W3 = (const float*)d_in[7];
    const float* b3 = (const float*)d_in[8];
    const float* Wa = (const float*)d_in[9];
    const float* ba = (const float*)d_in[10];
    float* out = (float*)d_out;

    float* ws = (float*)d_ws;
    float* hBuf = ws;                                   // 4*T*B*H
    float* cBuf = hBuf + (size_t)4 * TT * BB * HH;      // 4*T*B*S
    float* outA = cBuf + (size_t)4 * TT * BB * SS;      // B*OUTD
    float* outB = outA + (size_t)BB * OUTD;             // B*OUTD
    float* blockOutAll = outB + (size_t)BB * OUTD;      // T*B*OUTD

    const float* Wl[4] = {W0, W1, W2, W3};
    const float* bl[4] = {b0, b1, b2, b3};
    const int dil[4] = {1, 2, 4, 8};
    const int Kus[4] = {DIN, OUTD, OUTD, OUTD};

    dim3 blk(256), grd(256);
    for (int t = 0; t < TT; ++t) {
        for (int l = 0; l < 4; ++l) {
            const float* u;
            float* outp;
            const float* resid = nullptr;
            if (l == 0)      u = x + (size_t)t * BB * DIN;
            else if (l == 1) u = outA;
            else if (l == 2) u = outB;
            else             u = outA;
            if (l == 0)      outp = outA;
            else if (l == 1) outp = outB;
            else if (l == 2) outp = outA;
            else { outp = blockOutAll + (size_t)t * BB * OUTD; resid = outB; }

            float* hL = hBuf + (size_t)l * TT * BB * HH;
            float* cL = cBuf + (size_t)l * TT * BB * SS;
            const int d = dil[l];
            const int prev_ok = (t > 0) ? 1 : 0;
            const int delayed_ok = (t >= d) ? 1 : 0;
            const int tm1 = (t > 0) ? t - 1 : 0;
            const int td  = delayed_ok ? t - d : tm1;
            const float* hPrev = hL + (size_t)tm1 * BB * HH;
            const float* hDel  = hL + (size_t)td  * BB * HH;
            const float* cPrev = cL + (size_t)tm1 * BB * SS;
            const float* cDel  = cL + (size_t)td  * BB * SS;
            float* hOut = hL + (size_t)t * BB * HH;
            float* cOut = cL + (size_t)t * BB * SS;

            hipLaunchKernelGGL(cell_kernel, grd, blk, 0, stream,
                u, Kus[l], Wl[l], Kus[l] + 2 * HH, bl[l],
                hPrev, hDel, cPrev, cDel, prev_ok, delayed_ok,
                outp, resid, hOut, cOut);
        }
    }

    dim3 agrd(DOUT / 16, (TT * BB) / 64);
    hipLaunchKernelGGL(adaptor_kernel, agrd, blk, 0, stream,
                       blockOutAll, Wa, ba, out);
}

// Round 3
// 1061.954 us; speedup vs baseline: 8.0803x; 2.8933x over previous
//
#include <hip/hip_runtime.h>

#define BB   64
#define SS   1024
#define HH   256
#define OUTD 768
#define TT   16
#define DOUT 512
#define DIN  512

typedef __attribute__((ext_vector_type(8))) short short8;
typedef __attribute__((ext_vector_type(4))) short short4v;
typedef __attribute__((ext_vector_type(4))) float f32x4;

__device__ __forceinline__ unsigned short f2bf(float f) {
    unsigned u = __builtin_bit_cast(unsigned, f);
    u += 0x7FFFu + ((u >> 16) & 1u);
    return (unsigned short)(u >> 16);
}
__device__ __forceinline__ float bf2f(unsigned short h) {
    unsigned u = ((unsigned)h) << 16;
    return __builtin_bit_cast(float, u);
}

// ---------------------------------------------------------------------------
// Cell GEMM: g[64][4096] = xh[64][K] @ W[4096][K]^T  (fp32 W -> hi/lo bf16
// on the fly, 3-pass MFMA; A panels pre-split into bf16 hi/lo).
// grid = 256 blocks (16 gate-rows each), 8 waves, 8-way K-split + LDS reduce.
// A = concat(u[64][Ku], hPrev[64][256], hDel[64][256]); h segs only if t>0.
// ---------------------------------------------------------------------------
__global__ __launch_bounds__(512) void gemm_cell(
    const float* __restrict__ W, int Kin, int Kslice,
    const unsigned short* __restrict__ uHi, const unsigned short* __restrict__ uLo, int Ku,
    const unsigned short* __restrict__ hPrevHi, const unsigned short* __restrict__ hPrevLo,
    const unsigned short* __restrict__ hDelHi,  const unsigned short* __restrict__ hDelLo,
    float* __restrict__ g)
{
    __shared__ float red[8 * 4 * 16 * 17];   // [wave][mtile][row16][17 pad]

    const int tid  = threadIdx.x;
    const int lane = tid & 63;
    const int w    = tid >> 6;
    const int n0   = blockIdx.x * 16;        // gate-row strip
    const int l15  = lane & 15;
    const int lk8  = (lane >> 4) * 8;

    f32x4 acc[4] = {{0,0,0,0},{0,0,0,0},{0,0,0,0},{0,0,0,0}};

    const float* Wrow = W + (size_t)(n0 + l15) * Kin + lk8;
    const int nsteps = Kslice >> 5;
    int kb = w * Kslice;
    for (int s = 0; s < nsteps; ++s, kb += 32) {
        // W frag (8 fp32 per lane) -> hi/lo bf16
        f32x4 wv0 = *reinterpret_cast<const f32x4*>(Wrow + kb);
        f32x4 wv1 = *reinterpret_cast<const f32x4*>(Wrow + kb + 4);
        short8 whi, wlo;
        #pragma unroll
        for (int j = 0; j < 4; ++j) {
            unsigned short hb = f2bf(wv0[j]);
            whi[j] = (short)hb; wlo[j] = (short)f2bf(wv0[j] - bf2f(hb));
            unsigned short hb2 = f2bf(wv1[j]);
            whi[4+j] = (short)hb2; wlo[4+j] = (short)f2bf(wv1[j] - bf2f(hb2));
        }
        // A segment resolve (wave-uniform)
        const unsigned short *pHi, *pLo; int stride, koff;
        if (kb < Ku)            { pHi = uHi;     pLo = uLo;     stride = Ku;  koff = kb; }
        else if (kb < Ku + 256) { pHi = hPrevHi; pLo = hPrevLo; stride = 256; koff = kb - Ku; }
        else                    { pHi = hDelHi;  pLo = hDelLo;  stride = 256; koff = kb - Ku - 256; }
        const int ao = koff + lk8;
        #pragma unroll
        for (int m = 0; m < 4; ++m) {
            const int r = m * 16 + l15;
            short8 ahi = *reinterpret_cast<const short8*>(pHi + (size_t)r * stride + ao);
            short8 alo = *reinterpret_cast<const short8*>(pLo + (size_t)r * stride + ao);
            acc[m] = __builtin_amdgcn_mfma_f32_16x16x32_bf16(ahi, whi, acc[m], 0, 0, 0);
            acc[m] = __builtin_amdgcn_mfma_f32_16x16x32_bf16(alo, whi, acc[m], 0, 0, 0);
            acc[m] = __builtin_amdgcn_mfma_f32_16x16x32_bf16(ahi, wlo, acc[m], 0, 0, 0);
        }
    }

    // partials -> LDS  (C/D layout: col = lane&15, row = (lane>>4)*4 + i)
    {
        const int c  = lane & 15;
        const int r4 = (lane >> 4) * 4;
        #pragma unroll
        for (int m = 0; m < 4; ++m)
            #pragma unroll
            for (int i = 0; i < 4; ++i)
                red[(w * 4 + m) * 272 + (r4 + i) * 17 + c] = acc[m][i];
    }
    __syncthreads();

    #pragma unroll
    for (int e2 = 0; e2 < 2; ++e2) {
        const int e  = tid + e2 * 512;
        const int m  = e >> 8;
        const int rr = (e >> 4) & 15;
        const int c  = e & 15;
        float sum = 0.f;
        #pragma unroll
        for (int w2 = 0; w2 < 8; ++w2)
            sum += red[(w2 * 4 + m) * 272 + rr * 17 + c];
        g[(size_t)(m * 16 + rr) * 4096 + n0 + c] = sum;
    }
}

// ---------------------------------------------------------------------------
// Gate epilogue for one phase: reads g, applies LSTM math, writes c (fp32),
// h (bf16 hi/lo), and the next layer's input panel (bf16 hi/lo, optionally
// +resid, optionally fp32 copy). grid = 64 (batch row), block = 256.
// ---------------------------------------------------------------------------
__global__ __launch_bounds__(256) void epi_cell(
    const float* __restrict__ g, const float* __restrict__ bias,
    const float* __restrict__ cPrev, const float* __restrict__ cDel,
    int prev_ok, int delayed_ok,
    float* __restrict__ cOut,
    unsigned short* __restrict__ uHi, unsigned short* __restrict__ uLo,
    float* __restrict__ f32out,
    const float* __restrict__ resid,
    unsigned short* __restrict__ hHi, unsigned short* __restrict__ hLo)
{
    const int r  = blockIdx.x;
    const int j0 = threadIdx.x * 4;
    const float* gr = g + (size_t)r * 4096 + j0;
    f32x4 G0 = *reinterpret_cast<const f32x4*>(gr);
    f32x4 G1 = *reinterpret_cast<const f32x4*>(gr + 1024);
    f32x4 G2 = *reinterpret_cast<const f32x4*>(gr + 2048);
    f32x4 G3 = *reinterpret_cast<const f32x4*>(gr + 3072);
    f32x4 B0 = *reinterpret_cast<const f32x4*>(bias + j0);
    f32x4 B1 = *reinterpret_cast<const f32x4*>(bias + 1024 + j0);
    f32x4 B2 = *reinterpret_cast<const f32x4*>(bias + 2048 + j0);
    f32x4 B3 = *reinterpret_cast<const f32x4*>(bias + 3072 + j0);

    f32x4 pC = {0,0,0,0};
    if (prev_ok)    pC = *reinterpret_cast<const f32x4*>(cPrev + (size_t)r * SS + j0);
    f32x4 dC = pC;
    if (delayed_ok) dC = *reinterpret_cast<const f32x4*>(cDel + (size_t)r * SS + j0);

    f32x4 nf_v, wh_v;
    #pragma unroll
    for (int i = 0; i < 4; ++i) {
        float f = 1.f / (1.f + __expf(-(G0[i] + B0[i] + 1.f)));
        float n = tanhf(G1[i] + B1[i]);
        float a = 1.f / (1.f + __expf(-(G2[i] + B2[i])));
        float o = 1.f / (1.f + __expf(-(G3[i] + B3[i])));
        float wC = delayed_ok ? (a * pC[i] + (1.f - a) * dC[i]) : pC[i];
        float nf = prev_ok ? (f * wC + (1.f - f) * n) : n;
        nf_v[i] = nf;
        wh_v[i] = o * nf;
    }
    *reinterpret_cast<f32x4*>(cOut + (size_t)r * SS + j0) = nf_v;

    if (j0 < OUTD) {
        f32x4 v = wh_v;
        if (resid) {
            f32x4 rv = *reinterpret_cast<const f32x4*>(resid + (size_t)r * OUTD + j0);
            #pragma unroll
            for (int i = 0; i < 4; ++i) v[i] += rv[i];
        }
        if (f32out)
            *reinterpret_cast<f32x4*>(f32out + (size_t)r * OUTD + j0) = v;
        if (uHi) {
            short4v sh, sl;
            #pragma unroll
            for (int i = 0; i < 4; ++i) {
                unsigned short hb = f2bf(v[i]);
                sh[i] = (short)hb; sl[i] = (short)f2bf(v[i] - bf2f(hb));
            }
            *reinterpret_cast<short4v*>(uHi + (size_t)r * OUTD + j0) = sh;
            *reinterpret_cast<short4v*>(uLo + (size_t)r * OUTD + j0) = sl;
        }
    } else {
        const int jo = j0 - OUTD;
        short4v sh, sl;
        #pragma unroll
        for (int i = 0; i < 4; ++i) {
            unsigned short hb = f2bf(wh_v[i]);
            sh[i] = (short)hb; sl[i] = (short)f2bf(wh_v[i] - bf2f(hb));
        }
        *reinterpret_cast<short4v*>(hHi + (size_t)r * HH + jo) = sh;
        *reinterpret_cast<short4v*>(hLo + (size_t)r * HH + jo) = sl;
    }
}

// ---------------------------------------------------------------------------
// Adaptor: Y[1024][512] = A[1024][768] @ Wa[512][768]^T + ba, 3-pass MFMA.
// grid = (32 col-strips, 4 row-groups), 8 waves; wave = 32 rows x 16 cols.
// ---------------------------------------------------------------------------
__global__ __launch_bounds__(512) void adaptor_mfma(
    const unsigned short* __restrict__ Ahi, const unsigned short* __restrict__ Alo,
    const float* __restrict__ Wa, const float* __restrict__ ba,
    float* __restrict__ Y)
{
    const int tid  = threadIdx.x;
    const int lane = tid & 63;
    const int w    = tid >> 6;
    const int n0   = blockIdx.x * 16;
    const int r0   = blockIdx.y * 256 + w * 32;
    const int l15  = lane & 15;
    const int lk8  = (lane >> 4) * 8;

    f32x4 acc[2] = {{0,0,0,0},{0,0,0,0}};
    const float* Wrow = Wa + (size_t)(n0 + l15) * OUTD + lk8;
    for (int kb = 0; kb < OUTD; kb += 32) {
        f32x4 wv0 = *reinterpret_cast<const f32x4*>(Wrow + kb);
        f32x4 wv1 = *reinterpret_cast<const f32x4*>(Wrow + kb + 4);
        short8 whi, wlo;
        #pragma unroll
        for (int j = 0; j < 4; ++j) {
            unsigned short hb = f2bf(wv0[j]);
            whi[j] = (short)hb; wlo[j] = (short)f2bf(wv0[j] - bf2f(hb));
            unsigned short hb2 = f2bf(wv1[j]);
            whi[4+j] = (short)hb2; wlo[4+j] = (short)f2bf(wv1[j] - bf2f(hb2));
        }
        #pragma unroll
        for (int m = 0; m < 2; ++m) {
            const int r = r0 + m * 16 + l15;
            short8 ahi = *reinterpret_cast<const short8*>(Ahi + (size_t)r * OUTD + kb + lk8);
            short8 alo = *reinterpret_cast<const short8*>(Alo + (size_t)r * OUTD + kb + lk8);
            acc[m] = __builtin_amdgcn_mfma_f32_16x16x32_bf16(ahi, whi, acc[m], 0, 0, 0);
            acc[m] = __builtin_amdgcn_mfma_f32_16x16x32_bf16(alo, whi, acc[m], 0, 0, 0);
            acc[m] = __builtin_amdgcn_mfma_f32_16x16x32_bf16(ahi, wlo, acc[m], 0, 0, 0);
        }
    }
    const int c  = lane & 15;
    const int r4 = (lane >> 4) * 4;
    const float bb = ba[n0 + c];
    #pragma unroll
    for (int m = 0; m < 2; ++m)
        #pragma unroll
        for (int i = 0; i < 4; ++i)
            Y[(size_t)(r0 + m * 16 + r4 + i) * DOUT + n0 + c] = acc[m][i] + bb;
}

// ---------------------------------------------------------------------------
// fp32 -> bf16 hi/lo splitter (for the raw input x).
// ---------------------------------------------------------------------------
__global__ __launch_bounds__(256) void prep_split(
    const float* __restrict__ in, unsigned short* __restrict__ hi,
    unsigned short* __restrict__ lo, int n4)
{
    int i = blockIdx.x * 256 + threadIdx.x;
    if (i < n4) {
        f32x4 v = *reinterpret_cast<const f32x4*>(in + (size_t)i * 4);
        short4v sh, sl;
        #pragma unroll
        for (int j = 0; j < 4; ++j) {
            unsigned short hb = f2bf(v[j]);
            sh[j] = (short)hb; sl[j] = (short)f2bf(v[j] - bf2f(hb));
        }
        *reinterpret_cast<short4v*>(hi + (size_t)i * 4) = sh;
        *reinterpret_cast<short4v*>(lo + (size_t)i * 4) = sl;
    }
}

// ---------------------------------------------------------------------------
extern "C" void kernel_launch(void* const* d_in, const int* in_sizes, int n_in,
                              void* d_out, int out_size, void* d_ws, size_t ws_size,
                              hipStream_t stream)
{
    const float* x  = (const float*)d_in[0];
    const float* Wl[4] = {(const float*)d_in[1], (const float*)d_in[3],
                          (const float*)d_in[5], (const float*)d_in[7]};
    const float* bl[4] = {(const float*)d_in[2], (const float*)d_in[4],
                          (const float*)d_in[6], (const float*)d_in[8]};
    const float* Wa = (const float*)d_in[9];
    const float* ba = (const float*)d_in[10];
    float* out = (float*)d_out;

    // ---- workspace carve-up ----
    char* p = (char*)d_ws;
    auto take = [&](size_t bytes) { void* q = p; p += (bytes + 255) & ~(size_t)255; return q; };
    const size_t NX  = (size_t)TT * BB * DIN;        // 524288
    const size_t NH  = (size_t)BB * HH;              // per (l,t) panel
    const size_t NC  = (size_t)BB * SS;
    const size_t NO  = (size_t)BB * OUTD;
    unsigned short* xHi = (unsigned short*)take(NX * 2);
    unsigned short* xLo = (unsigned short*)take(NX * 2);
    unsigned short* hHi = (unsigned short*)take(4 * TT * NH * 2);
    unsigned short* hLo = (unsigned short*)take(4 * TT * NH * 2);
    float*          cB  = (float*)take(4 * TT * NC * 4);
    unsigned short* o0Hi = (unsigned short*)take(TT * NO * 2);
    unsigned short* o0Lo = (unsigned short*)take(TT * NO * 2);
    unsigned short* o1Hi = (unsigned short*)take(TT * NO * 2);
    unsigned short* o1Lo = (unsigned short*)take(TT * NO * 2);
    float*          o1F  = (float*)take(TT * NO * 4);
    unsigned short* o2Hi = (unsigned short*)take(TT * NO * 2);
    unsigned short* o2Lo = (unsigned short*)take(TT * NO * 2);
    unsigned short* fHi  = (unsigned short*)take(TT * NO * 2);
    unsigned short* fLo  = (unsigned short*)take(TT * NO * 2);
    float*          g    = (float*)take((size_t)BB * 4 * SS * 4);

    // ---- input split ----
    hipLaunchKernelGGL(prep_split, dim3((NX / 4 + 255) / 256), dim3(256), 0, stream,
                       x, xHi, xLo, (int)(NX / 4));

    const int dil[4] = {1, 2, 4, 8};
    unsigned short* uHis[4] = {xHi, o0Hi, o1Hi, o2Hi};
    unsigned short* uLos[4] = {xLo, o0Lo, o1Lo, o2Lo};

    for (int l = 0; l < 4; ++l) {
        const int Ku  = (l == 0) ? DIN : OUTD;
        const int Kin = Ku + 2 * HH;
        const size_t ustride = (size_t)BB * Ku;
        unsigned short* hHl = hHi + (size_t)l * TT * NH;
        unsigned short* hLl = hLo + (size_t)l * TT * NH;
        float* cL = cB + (size_t)l * TT * NC;

        for (int t = 0; t < TT; ++t) {
            const int prev_ok = (t > 0);
            const int d = dil[l];
            const int delayed_ok = (t >= d);
            const int tm1 = prev_ok ? t - 1 : 0;
            const int td  = delayed_ok ? t - d : tm1;
            const int Keff = prev_ok ? Kin : Ku;
            const int Kslice = Keff / 8;

            hipLaunchKernelGGL(gemm_cell, dim3(256), dim3(512), 0, stream,
                Wl[l], Kin, Kslice,
                uHis[l] + (size_t)t * ustride, uLos[l] + (size_t)t * ustride, Ku,
                hHl + (size_t)tm1 * NH, hLl + (size_t)tm1 * NH,
                hHl + (size_t)td  * NH, hLl + (size_t)td  * NH,
                g);

            unsigned short *duHi, *duLo; float* f32out; const float* resid;
            if (l == 0)      { duHi = o0Hi + (size_t)t * NO; duLo = o0Lo + (size_t)t * NO; f32out = nullptr; resid = nullptr; }
            else if (l == 1) { duHi = o1Hi + (size_t)t * NO; duLo = o1Lo + (size_t)t * NO; f32out = o1F + (size_t)t * NO; resid = nullptr; }
            else if (l == 2) { duHi = o2Hi + (size_t)t * NO; duLo = o2Lo + (size_t)t * NO; f32out = nullptr; resid = nullptr; }
            else             { duHi = fHi  + (size_t)t * NO; duLo = fLo  + (size_t)t * NO; f32out = nullptr; resid = o1F + (size_t)t * NO; }

            hipLaunchKernelGGL(epi_cell, dim3(64), dim3(256), 0, stream,
                g, bl[l],
                cL + (size_t)tm1 * NC, cL + (size_t)td * NC,
                prev_ok, delayed_ok,
                cL + (size_t)t * NC,
                duHi, duLo, f32out, resid,
                hHl + (size_t)t * NH, hLl + (size_t)t * NH);
        }
    }

    hipLaunchKernelGGL(adaptor_mfma, dim3(DOUT / 16, 4), dim3(512), 0, stream,
                       fHi, fLo, Wa, ba, out);
}